// Round 4
// baseline (1423.547 us; speedup 1.0000x reference)
//
#include <hip/hip_runtime.h>
#include <cmath>

// LAGCNII round 4: FUSED agg+GEMM per layer (no x intermediate, barrier-free
// MFMA phase with B-frags straight from L2-resident W), pipelined lin.
// ws: h0|bufA|bufB bf16 (153.6MB) + bf16 W^T + CSR ints.

#define N_NODES 100000
#define N_EDGES 300000
#define DIN 256
#define CHN 256
#define DHID 128
#define NCLASS 40
#define NLAYER 8
#define SCAN_NB 98

typedef short bf16x8 __attribute__((ext_vector_type(8)));
typedef float f32x4 __attribute__((ext_vector_type(4)));

__device__ inline short f2bf(float f) {
  unsigned u = __float_as_uint(f);
  unsigned r = (u + 0x7FFFu + ((u >> 16) & 1u)) >> 16;
  return (short)r;
}
__device__ inline float bf2f(short s) {
  return __uint_as_float(((unsigned)(unsigned short)s) << 16);
}

// ---------------- CSR build (by dst) ----------------
__global__ void hist_kernel(const int* __restrict__ dst, int* __restrict__ cnt) {
  int e = blockIdx.x * 256 + threadIdx.x;
  if (e < N_EDGES) atomicAdd(&cnt[dst[e]], 1);
}

__global__ __launch_bounds__(256) void bscan1(const int* __restrict__ cnt,
                                              int* __restrict__ rowp,
                                              int* __restrict__ bsums) {
  int tid = threadIdx.x;
  int base = blockIdx.x * 1024 + tid * 4;
  int v0 = 0, v1 = 0, v2 = 0, v3 = 0;
  if (base + 3 < N_NODES) {
    int4 v = *(const int4*)(cnt + base);
    v0 = v.x; v1 = v.y; v2 = v.z; v3 = v.w;
  } else {
    if (base + 0 < N_NODES) v0 = cnt[base + 0];
    if (base + 1 < N_NODES) v1 = cnt[base + 1];
    if (base + 2 < N_NODES) v2 = cnt[base + 2];
    if (base + 3 < N_NODES) v3 = cnt[base + 3];
  }
  int t = v0 + v1 + v2 + v3;
  int lane = tid & 63;
  int incl = t;
#pragma unroll
  for (int off = 1; off < 64; off <<= 1) {
    int x = __shfl_up(incl, off, 64);
    if (lane >= off) incl += x;
  }
  __shared__ int wsum[4];
  int wave = tid >> 6;
  if (lane == 63) wsum[wave] = incl;
  __syncthreads();
  int woff = 0;
  for (int w = 0; w < wave; w++) woff += wsum[w];
  int excl = woff + incl - t;
  int e0 = excl, e1 = e0 + v0, e2 = e1 + v1, e3 = e2 + v2;
  if (base + 0 < N_NODES) rowp[base + 0] = e0;
  if (base + 1 < N_NODES) rowp[base + 1] = e1;
  if (base + 2 < N_NODES) rowp[base + 2] = e2;
  if (base + 3 < N_NODES) rowp[base + 3] = e3;
  if (tid == 255) bsums[blockIdx.x] = woff + incl;
}

__global__ void bscan2(int* __restrict__ bsums, int* __restrict__ rowp) {
  if (threadIdx.x == 0 && blockIdx.x == 0) {
    int s = 0;
    for (int i = 0; i < SCAN_NB; i++) {
      int v = bsums[i];
      bsums[i] = s;
      s += v;
    }
    rowp[N_NODES] = s;
  }
}

__global__ __launch_bounds__(256) void bscan3(int* __restrict__ rowp,
                                              int* __restrict__ fill,
                                              const int* __restrict__ bsums) {
  int base = blockIdx.x * 1024 + threadIdx.x * 4;
  int off = bsums[blockIdx.x];
#pragma unroll
  for (int j = 0; j < 4; j++) {
    int i = base + j;
    if (i < N_NODES) {
      int p = rowp[i] + off;
      rowp[i] = p;
      fill[i] = p;
    }
  }
}

__global__ void scatter_kernel(const int* __restrict__ src, const int* __restrict__ dst,
                               int* __restrict__ fill, int* __restrict__ col) {
  int e = blockIdx.x * 256 + threadIdx.x;
  if (e < N_EDGES) {
    int p = atomicAdd(&fill[dst[e]], 1);
    col[p] = src[e];
  }
}

// ---------------- weight prep: bf16 transposed weights ----------------
__global__ void prep_w_kernel(const float* __restrict__ lw, const float* __restrict__ gw,
                              short* __restrict__ linT, short* __restrict__ gcnT) {
  int i = blockIdx.x * 256 + threadIdx.x;
  if (i < 2 * 128 * 256) {
    int v = i >> 15;
    int rem = i & 32767;
    int n = rem >> 8;
    int k = rem & 255;
    linT[i] = f2bf(lw[v * (DIN * DHID) + k * DHID + n]);
  }
  int j = i - 2 * 128 * 256;
  if (j >= 0 && j < 8 * 256 * 256) {
    int l = j >> 16;
    int rem = j & 65535;
    int n = rem >> 8;
    int k = rem & 255;
    gcnT[j] = f2bf(gw[l * (CHN * CHN) + k * CHN + n]);
  }
}

// ---------------- lin: h0[:, v*128+n] = relu(Xv @ Wv + bv), bf16 out ----------------
// 64x128 tile, 4 waves (each 32x64), BK=32, register-prefetch pipeline.
__global__ __launch_bounds__(256) void lin_mfma_kernel(const float* __restrict__ x0,
                                                       const float* __restrict__ x1,
                                                       const short* __restrict__ linT,
                                                       const float* __restrict__ lb,
                                                       short* __restrict__ h0) {
  const int view = blockIdx.y;
  const float* __restrict__ X = view ? x1 : x0;
  const short* __restrict__ Wt = linT + view * (DHID * DIN);  // [n][k]
  const int row0 = blockIdx.x * 64;
  __shared__ short As[64 * 40];
  __shared__ short Bs[128 * 40];
  const int tid = threadIdx.x;
  const int lane = tid & 63, wave = tid >> 6;
  const int quad = lane >> 4, mrem = lane & 15;
  const int wrow = (wave & 1) * 32, wcol = (wave >> 1) * 64;

  f32x4 acc[2][4];
#pragma unroll
  for (int i = 0; i < 2; i++)
#pragma unroll
    for (int j = 0; j < 4; j++) acc[i][j] = (f32x4){0.f, 0.f, 0.f, 0.f};

  const int ar = tid >> 2;        // 0..63
  const int ak = (tid & 3) * 8;   // 0,8,16,24
  const int br = tid >> 1;        // 0..127
  const int bk = (tid & 1) * 16;  // 0,16

  float av[8];
  bf16x8 bv0, bv1;
  const int gr = row0 + ar;
  {
    if (gr < N_NODES) {
      const float* p = X + (size_t)gr * DIN + ak;
      *(float4*)(av) = *(const float4*)p;
      *(float4*)(av + 4) = *(const float4*)(p + 4);
    } else {
#pragma unroll
      for (int z = 0; z < 8; z++) av[z] = 0.f;
    }
    const short* p = Wt + (size_t)br * DIN + bk;
    bv0 = *(const bf16x8*)p;
    bv1 = *(const bf16x8*)(p + 8);
  }

  for (int c = 0; c < 8; c++) {
    if (c) __syncthreads();
    {
      short s8[8];
#pragma unroll
      for (int z = 0; z < 8; z++) s8[z] = f2bf(av[z]);
      *(bf16x8*)&As[ar * 40 + ak] = *(bf16x8*)s8;
      *(bf16x8*)&Bs[br * 40 + bk] = bv0;
      *(bf16x8*)&Bs[br * 40 + bk + 8] = bv1;
    }
    __syncthreads();
    if (c < 7) {
      int k0 = (c + 1) * 32;
      if (gr < N_NODES) {
        const float* p = X + (size_t)gr * DIN + k0 + ak;
        *(float4*)(av) = *(const float4*)p;
        *(float4*)(av + 4) = *(const float4*)(p + 4);
      }
      const short* p = Wt + (size_t)br * DIN + k0 + bk;
      bv0 = *(const bf16x8*)p;
      bv1 = *(const bf16x8*)(p + 8);
    }
    bf16x8 af[2], bfr[4];
#pragma unroll
    for (int i = 0; i < 2; i++) af[i] = *(const bf16x8*)&As[(wrow + i * 16 + mrem) * 40 + quad * 8];
#pragma unroll
    for (int j = 0; j < 4; j++) bfr[j] = *(const bf16x8*)&Bs[(wcol + j * 16 + mrem) * 40 + quad * 8];
#pragma unroll
    for (int i = 0; i < 2; i++)
#pragma unroll
      for (int j = 0; j < 4; j++)
        acc[i][j] = __builtin_amdgcn_mfma_f32_16x16x32_bf16(af[i], bfr[j], acc[i][j], 0, 0, 0);
  }
#pragma unroll
  for (int i = 0; i < 2; i++) {
#pragma unroll
    for (int j = 0; j < 4; j++) {
      int lcol = wcol + j * 16 + mrem;  // 0..127
      float bb = lb[view * DHID + lcol];
#pragma unroll
      for (int r = 0; r < 4; r++) {
        int grow = row0 + wrow + i * 16 + quad * 4 + r;
        if (grow < N_NODES)
          h0[(size_t)grow * CHN + view * DHID + lcol] = f2bf(fmaxf(acc[i][j][r] + bb, 0.f));
      }
    }
  }
}

// ---------------- fused layer: agg + GEMM + residual + relu ----------------
// Block 256 thr, 64 rows x 256 cols. Phase 1: gather agg -> bf16 A-tile in LDS.
// Phase 2: barrier-free MFMA, B-frags straight from global (L2-resident W).
__global__ __launch_bounds__(256) void fused_layer_kernel(const short* __restrict__ h,
                                                          const short* __restrict__ h0,
                                                          const int* __restrict__ rowp,
                                                          const int* __restrict__ col,
                                                          const short* __restrict__ Wt,  // [n][k]
                                                          short* __restrict__ hout,
                                                          float beta) {
  const int row0 = blockIdx.x * 64;
  __shared__ short As[64 * 264];  // [row][k], +8 pad
  const int tid = threadIdx.x;

  // ---- Phase 1: aggregate; thread t: row = row0+(t>>2), channels (t&3)*64 ..+64
  {
    const int lr = tid >> 2;
    const int r = row0 + lr;
    const int cb = (tid & 3) * 64;
    if (r < N_NODES) {
      float acc[64];
#pragma unroll
      for (int z = 0; z < 64; z++) acc[z] = 0.f;
      int beg = rowp[r], end = rowp[r + 1];
      for (int e = beg; e < end; ++e) {
        int s = col[e];
        const short* p = h + (size_t)s * CHN + cb;
#pragma unroll
        for (int q = 0; q < 8; q++) {
          bf16x8 v = *(const bf16x8*)(p + q * 8);
#pragma unroll
          for (int z = 0; z < 8; z++) acc[q * 8 + z] += bf2f(v[z]);
        }
      }
      const short* p0 = h0 + (size_t)r * CHN + cb;
#pragma unroll
      for (int q = 0; q < 8; q++) {
        bf16x8 v0 = *(const bf16x8*)(p0 + q * 8);
        short s8[8];
#pragma unroll
        for (int z = 0; z < 8; z++)
          s8[z] = f2bf(0.9f * acc[q * 8 + z] + 0.1f * bf2f(v0[z]));
        *(bf16x8*)&As[lr * 264 + cb + q * 8] = *(bf16x8*)s8;
      }
    } else {
      bf16x8 zz = (bf16x8)(short)0;
#pragma unroll
      for (int q = 0; q < 8; q++) *(bf16x8*)&As[lr * 264 + cb + q * 8] = zz;
    }
  }
  __syncthreads();

  // ---- Phase 2: GEMM, 4 waves: wrow=(w&1)*32, wcol=(w>>1)*128
  const int lane = tid & 63, wave = tid >> 6;
  const int quad = lane >> 4, mrem = lane & 15;
  const int wrow = (wave & 1) * 32, wcol = (wave >> 1) * 128;

  f32x4 acc[2][8];
#pragma unroll
  for (int i = 0; i < 2; i++)
#pragma unroll
    for (int j = 0; j < 8; j++) acc[i][j] = (f32x4){0.f, 0.f, 0.f, 0.f};

#pragma unroll
  for (int c = 0; c < 8; c++) {
    const int k0 = c * 32;
    bf16x8 af[2];
    af[0] = *(const bf16x8*)&As[(wrow + mrem) * 264 + k0 + quad * 8];
    af[1] = *(const bf16x8*)&As[(wrow + 16 + mrem) * 264 + k0 + quad * 8];
#pragma unroll
    for (int j = 0; j < 8; j++) {
      bf16x8 bfr = *(const bf16x8*)(Wt + (size_t)(wcol + j * 16 + mrem) * CHN + k0 + quad * 8);
      acc[0][j] = __builtin_amdgcn_mfma_f32_16x16x32_bf16(af[0], bfr, acc[0][j], 0, 0, 0);
      acc[1][j] = __builtin_amdgcn_mfma_f32_16x16x32_bf16(af[1], bfr, acc[1][j], 0, 0, 0);
    }
  }

  const float omb = 1.f - beta;
#pragma unroll
  for (int i = 0; i < 2; i++) {
#pragma unroll
    for (int j = 0; j < 8; j++) {
      int lcol = wcol + j * 16 + mrem;  // 0..255
#pragma unroll
      for (int r = 0; r < 4; r++) {
        int lrow = wrow + i * 16 + quad * 4 + r;  // 0..63
        int grow = row0 + lrow;
        if (grow < N_NODES) {
          float xv = bf2f(As[lrow * 264 + lcol]);
          hout[(size_t)grow * CHN + lcol] = f2bf(fmaxf(omb * xv + beta * acc[i][j][r], 0.f));
        }
      }
    }
  }
}

// ---------------- out: out = h @ Wo + bo  (M=100000, K=256, N=40) ----------------
__global__ __launch_bounds__(256) void out_kernel(const short* __restrict__ h,
                                                  const float* __restrict__ W,
                                                  const float* __restrict__ b,
                                                  float* __restrict__ out) {
  __shared__ float xs[32][260];
  __shared__ float ws[64][40];
  const int row0 = blockIdx.x * 32;
  const int tid = threadIdx.x;
  for (int f = tid; f < 1024; f += 256) {
    int r = f >> 5;
    int c = (f & 31) * 8;
    bf16x8 v = *(const bf16x8*)(h + (size_t)(row0 + r) * CHN + c);
    float t0[8];
#pragma unroll
    for (int q = 0; q < 8; q++) t0[q] = bf2f(v[q]);
    *(float4*)&xs[r][c] = *(float4*)(t0);
    *(float4*)&xs[r][c + 4] = *(float4*)(t0 + 4);
  }
  const int r = tid >> 3;
  const int cg = (tid & 7) * 5;
  float acc[5];
#pragma unroll
  for (int j = 0; j < 5; j++) acc[j] = b[cg + j];
  for (int k0 = 0; k0 < CHN; k0 += 64) {
    for (int i = tid; i < 64 * 40; i += 256) {
      int k = i / 40, c = i % 40;
      ws[k][c] = W[(size_t)(k0 + k) * NCLASS + c];
    }
    __syncthreads();
#pragma unroll 8
    for (int k = 0; k < 64; k++) {
      float xv = xs[r][k0 + k];
#pragma unroll
      for (int j = 0; j < 5; j++) acc[j] += xv * ws[k][cg + j];
    }
    __syncthreads();
  }
  float* op = out + (size_t)(row0 + r) * NCLASS + cg;
#pragma unroll
  for (int j = 0; j < 5; j++) op[j] = acc[j];
}

extern "C" void kernel_launch(void* const* d_in, const int* in_sizes, int n_in,
                              void* d_out, int out_size, void* d_ws, size_t ws_size,
                              hipStream_t stream) {
  const float* x0 = (const float*)d_in[0];
  const float* x1 = (const float*)d_in[1];
  const int* ei = (const int*)d_in[2];
  const float* lw = (const float*)d_in[3];
  const float* lb = (const float*)d_in[4];
  const float* gw = (const float*)d_in[5];
  const float* ow = (const float*)d_in[6];
  const float* ob = (const float*)d_in[7];
  float* outp = (float*)d_out;

  const size_t NC = (size_t)N_NODES * CHN;
  short* h0 = (short*)d_ws;
  short* bufA = h0 + NC;
  short* bufB = bufA + NC;
  short* linT = bufB + NC;
  short* gcnT = linT + 2 * DHID * DIN;
  int* cnt = (int*)(gcnT + 8 * CHN * CHN);
  int* rowp = cnt + N_NODES;
  int* fill = rowp + N_NODES + 1;
  int* col = fill + N_NODES;
  int* bsums = col + N_EDGES;

  const int* src = ei;
  const int* dst = ei + N_EDGES;

  hipMemsetAsync(cnt, 0, N_NODES * sizeof(int), stream);
  hist_kernel<<<(N_EDGES + 255) / 256, 256, 0, stream>>>(dst, cnt);
  bscan1<<<SCAN_NB, 256, 0, stream>>>(cnt, rowp, bsums);
  bscan2<<<1, 64, 0, stream>>>(bsums, rowp);
  bscan3<<<SCAN_NB, 256, 0, stream>>>(rowp, fill, bsums);
  scatter_kernel<<<(N_EDGES + 255) / 256, 256, 0, stream>>>(src, dst, fill, col);
  prep_w_kernel<<<(2 * 128 * 256 + 8 * 256 * 256 + 255) / 256, 256, 0, stream>>>(lw, gw, linT, gcnT);

  dim3 lg((N_NODES + 63) / 64, 2);
  lin_mfma_kernel<<<lg, 256, 0, stream>>>(x0, x1, linT, lb, h0);

  const int nblk = (N_NODES + 63) / 64;
  const short* hin = h0;
  short* outs[2] = {bufA, bufB};
  for (int l = 0; l < NLAYER; ++l) {
    float beta = logf(0.5f / (float)(l + 1) + 1.0f);
    short* ho = outs[l & 1];
    fused_layer_kernel<<<nblk, 256, 0, stream>>>(hin, h0, rowp, col,
                                                 gcnT + (size_t)l * CHN * CHN, ho, beta);
    hin = ho;
  }
  out_kernel<<<N_NODES / 32, 256, 0, stream>>>(bufB, ow, ob, outp);
}

// Round 5
// 1337.721 us; speedup vs baseline: 1.0642x; 1.0642x over previous
//
#include <hip/hip_runtime.h>
#include <cmath>

// LAGCNII round 5: un-fused (fusion was latency-bound at 4 blocks/CU).
// agg: wave/node, no LDS, 32 waves/CU, edge-pair MLP.
// gemm: A-stage->LDS once, barrier-free MFMA with B from L2-resident W,
//       residual read from LDS (x read once from global).

#define N_NODES 100000
#define N_EDGES 300000
#define DIN 256
#define CHN 256
#define DHID 128
#define NCLASS 40
#define NLAYER 8
#define SCAN_NB 98

typedef short bf16x8 __attribute__((ext_vector_type(8)));
typedef float f32x4 __attribute__((ext_vector_type(4)));

__device__ inline short f2bf(float f) {
  unsigned u = __float_as_uint(f);
  unsigned r = (u + 0x7FFFu + ((u >> 16) & 1u)) >> 16;
  return (short)r;
}
__device__ inline float bf2f(short s) {
  return __uint_as_float(((unsigned)(unsigned short)s) << 16);
}

// ---------------- CSR build (by dst) ----------------
__global__ void hist_kernel(const int* __restrict__ dst, int* __restrict__ cnt) {
  int e = blockIdx.x * 256 + threadIdx.x;
  if (e < N_EDGES) atomicAdd(&cnt[dst[e]], 1);
}

__global__ __launch_bounds__(256) void bscan1(const int* __restrict__ cnt,
                                              int* __restrict__ rowp,
                                              int* __restrict__ bsums) {
  int tid = threadIdx.x;
  int base = blockIdx.x * 1024 + tid * 4;
  int v0 = 0, v1 = 0, v2 = 0, v3 = 0;
  if (base + 3 < N_NODES) {
    int4 v = *(const int4*)(cnt + base);
    v0 = v.x; v1 = v.y; v2 = v.z; v3 = v.w;
  } else {
    if (base + 0 < N_NODES) v0 = cnt[base + 0];
    if (base + 1 < N_NODES) v1 = cnt[base + 1];
    if (base + 2 < N_NODES) v2 = cnt[base + 2];
    if (base + 3 < N_NODES) v3 = cnt[base + 3];
  }
  int t = v0 + v1 + v2 + v3;
  int lane = tid & 63;
  int incl = t;
#pragma unroll
  for (int off = 1; off < 64; off <<= 1) {
    int x = __shfl_up(incl, off, 64);
    if (lane >= off) incl += x;
  }
  __shared__ int wsum[4];
  int wave = tid >> 6;
  if (lane == 63) wsum[wave] = incl;
  __syncthreads();
  int woff = 0;
  for (int w = 0; w < wave; w++) woff += wsum[w];
  int excl = woff + incl - t;
  int e0 = excl, e1 = e0 + v0, e2 = e1 + v1, e3 = e2 + v2;
  if (base + 0 < N_NODES) rowp[base + 0] = e0;
  if (base + 1 < N_NODES) rowp[base + 1] = e1;
  if (base + 2 < N_NODES) rowp[base + 2] = e2;
  if (base + 3 < N_NODES) rowp[base + 3] = e3;
  if (tid == 255) bsums[blockIdx.x] = woff + incl;
}

__global__ void bscan2(int* __restrict__ bsums, int* __restrict__ rowp) {
  if (threadIdx.x == 0 && blockIdx.x == 0) {
    int s = 0;
    for (int i = 0; i < SCAN_NB; i++) {
      int v = bsums[i];
      bsums[i] = s;
      s += v;
    }
    rowp[N_NODES] = s;
  }
}

__global__ __launch_bounds__(256) void bscan3(int* __restrict__ rowp,
                                              int* __restrict__ fill,
                                              const int* __restrict__ bsums) {
  int base = blockIdx.x * 1024 + threadIdx.x * 4;
  int off = bsums[blockIdx.x];
#pragma unroll
  for (int j = 0; j < 4; j++) {
    int i = base + j;
    if (i < N_NODES) {
      int p = rowp[i] + off;
      rowp[i] = p;
      fill[i] = p;
    }
  }
}

__global__ void scatter_kernel(const int* __restrict__ src, const int* __restrict__ dst,
                               int* __restrict__ fill, int* __restrict__ col) {
  int e = blockIdx.x * 256 + threadIdx.x;
  if (e < N_EDGES) {
    int p = atomicAdd(&fill[dst[e]], 1);
    col[p] = src[e];
  }
}

// ---------------- weight prep: bf16 transposed weights ----------------
__global__ void prep_w_kernel(const float* __restrict__ lw, const float* __restrict__ gw,
                              short* __restrict__ linT, short* __restrict__ gcnT) {
  int i = blockIdx.x * 256 + threadIdx.x;
  if (i < 2 * 128 * 256) {
    int v = i >> 15;
    int rem = i & 32767;
    int n = rem >> 8;
    int k = rem & 255;
    linT[i] = f2bf(lw[v * (DIN * DHID) + k * DHID + n]);
  }
  int j = i - 2 * 128 * 256;
  if (j >= 0 && j < 8 * 256 * 256) {
    int l = j >> 16;
    int rem = j & 65535;
    int n = rem >> 8;
    int k = rem & 255;
    gcnT[j] = f2bf(gw[l * (CHN * CHN) + k * CHN + n]);
  }
}

// ---------------- lin: h0[:, v*128+n] = relu(Xv @ Wv + bv), bf16 out ----------------
__global__ __launch_bounds__(256) void lin_mfma_kernel(const float* __restrict__ x0,
                                                       const float* __restrict__ x1,
                                                       const short* __restrict__ linT,
                                                       const float* __restrict__ lb,
                                                       short* __restrict__ h0) {
  const int view = blockIdx.y;
  const float* __restrict__ X = view ? x1 : x0;
  const short* __restrict__ Wt = linT + view * (DHID * DIN);  // [n][k]
  const int row0 = blockIdx.x * 64;
  __shared__ short As[64 * 40];
  __shared__ short Bs[128 * 40];
  const int tid = threadIdx.x;
  const int lane = tid & 63, wave = tid >> 6;
  const int quad = lane >> 4, mrem = lane & 15;
  const int wrow = (wave & 1) * 32, wcol = (wave >> 1) * 64;

  f32x4 acc[2][4];
#pragma unroll
  for (int i = 0; i < 2; i++)
#pragma unroll
    for (int j = 0; j < 4; j++) acc[i][j] = (f32x4){0.f, 0.f, 0.f, 0.f};

  const int ar = tid >> 2;
  const int ak = (tid & 3) * 8;
  const int br = tid >> 1;
  const int bk = (tid & 1) * 16;

  float av[8];
  bf16x8 bv0, bv1;
  const int gr = row0 + ar;
  {
    if (gr < N_NODES) {
      const float* p = X + (size_t)gr * DIN + ak;
      *(float4*)(av) = *(const float4*)p;
      *(float4*)(av + 4) = *(const float4*)(p + 4);
    } else {
#pragma unroll
      for (int z = 0; z < 8; z++) av[z] = 0.f;
    }
    const short* p = Wt + (size_t)br * DIN + bk;
    bv0 = *(const bf16x8*)p;
    bv1 = *(const bf16x8*)(p + 8);
  }

  for (int c = 0; c < 8; c++) {
    if (c) __syncthreads();
    {
      short s8[8];
#pragma unroll
      for (int z = 0; z < 8; z++) s8[z] = f2bf(av[z]);
      *(bf16x8*)&As[ar * 40 + ak] = *(bf16x8*)s8;
      *(bf16x8*)&Bs[br * 40 + bk] = bv0;
      *(bf16x8*)&Bs[br * 40 + bk + 8] = bv1;
    }
    __syncthreads();
    if (c < 7) {
      int k0 = (c + 1) * 32;
      if (gr < N_NODES) {
        const float* p = X + (size_t)gr * DIN + k0 + ak;
        *(float4*)(av) = *(const float4*)p;
        *(float4*)(av + 4) = *(const float4*)(p + 4);
      }
      const short* p = Wt + (size_t)br * DIN + k0 + bk;
      bv0 = *(const bf16x8*)p;
      bv1 = *(const bf16x8*)(p + 8);
    }
    bf16x8 af[2], bfr[4];
#pragma unroll
    for (int i = 0; i < 2; i++) af[i] = *(const bf16x8*)&As[(wrow + i * 16 + mrem) * 40 + quad * 8];
#pragma unroll
    for (int j = 0; j < 4; j++) bfr[j] = *(const bf16x8*)&Bs[(wcol + j * 16 + mrem) * 40 + quad * 8];
#pragma unroll
    for (int i = 0; i < 2; i++)
#pragma unroll
      for (int j = 0; j < 4; j++)
        acc[i][j] = __builtin_amdgcn_mfma_f32_16x16x32_bf16(af[i], bfr[j], acc[i][j], 0, 0, 0);
  }
#pragma unroll
  for (int i = 0; i < 2; i++) {
#pragma unroll
    for (int j = 0; j < 4; j++) {
      int lcol = wcol + j * 16 + mrem;
      float bb = lb[view * DHID + lcol];
#pragma unroll
      for (int r = 0; r < 4; r++) {
        int grow = row0 + wrow + i * 16 + quad * 4 + r;
        if (grow < N_NODES)
          h0[(size_t)grow * CHN + view * DHID + lcol] = f2bf(fmaxf(acc[i][j][r] + bb, 0.f));
      }
    }
  }
}

// ---------------- agg: x = 0.9*sum h[src] + 0.1*h0, wave/node, no LDS ----------------
__global__ __launch_bounds__(256, 8) void agg_kernel(const short* __restrict__ h,
                                                     const short* __restrict__ h0,
                                                     const int* __restrict__ rowp,
                                                     const int* __restrict__ col,
                                                     short* __restrict__ x) {
  int node = blockIdx.x * 4 + (threadIdx.x >> 6);
  int t = threadIdx.x & 63;
  int beg = rowp[node], end = rowp[node + 1];
  float a0 = 0.f, a1 = 0.f, a2 = 0.f, a3 = 0.f;
  int e = beg;
  for (; e + 1 < end; e += 2) {
    int s0 = col[e];
    int s1 = col[e + 1];
    short4 v0 = *(const short4*)(h + (size_t)s0 * CHN + t * 4);
    short4 v1 = *(const short4*)(h + (size_t)s1 * CHN + t * 4);
    a0 += bf2f(v0.x) + bf2f(v1.x);
    a1 += bf2f(v0.y) + bf2f(v1.y);
    a2 += bf2f(v0.z) + bf2f(v1.z);
    a3 += bf2f(v0.w) + bf2f(v1.w);
  }
  if (e < end) {
    int s = col[e];
    short4 v = *(const short4*)(h + (size_t)s * CHN + t * 4);
    a0 += bf2f(v.x); a1 += bf2f(v.y); a2 += bf2f(v.z); a3 += bf2f(v.w);
  }
  short4 r = *(const short4*)(h0 + (size_t)node * CHN + t * 4);
  short4 o;
  o.x = f2bf(0.9f * a0 + 0.1f * bf2f(r.x));
  o.y = f2bf(0.9f * a1 + 0.1f * bf2f(r.y));
  o.z = f2bf(0.9f * a2 + 0.1f * bf2f(r.z));
  o.w = f2bf(0.9f * a3 + 0.1f * bf2f(r.w));
  *(short4*)(x + (size_t)node * CHN + t * 4) = o;
}

// ---------------- layer GEMM v2: h = relu((1-b)*x + b*(x@W)) ----------------
// 64x256 tile. A staged to LDS once (1 barrier); MFMA loop barrier-free,
// B-frags from global (L2-resident 128KB W); residual read from LDS.
__global__ __launch_bounds__(256) void layer_gemm_v2(const short* __restrict__ x,
                                                     const short* __restrict__ Wt,  // [n][k]
                                                     short* __restrict__ hout, float beta) {
  const int row0 = blockIdx.x * 64;
  __shared__ short As[64 * 264];
  const int tid = threadIdx.x;
  {
    const int lr = tid >> 2;
    const int cb = (tid & 3) * 64;
    const int gr = row0 + lr;
    if (gr < N_NODES) {
      const short* p = x + (size_t)gr * CHN + cb;
#pragma unroll
      for (int q = 0; q < 8; q++)
        *(bf16x8*)&As[lr * 264 + cb + q * 8] = *(const bf16x8*)(p + q * 8);
    } else {
      bf16x8 zz = (bf16x8)(short)0;
#pragma unroll
      for (int q = 0; q < 8; q++) *(bf16x8*)&As[lr * 264 + cb + q * 8] = zz;
    }
  }
  __syncthreads();

  const int lane = tid & 63, wave = tid >> 6;
  const int quad = lane >> 4, mrem = lane & 15;
  const int wrow = (wave & 1) * 32, wcol = (wave >> 1) * 128;

  f32x4 acc[2][8];
#pragma unroll
  for (int i = 0; i < 2; i++)
#pragma unroll
    for (int j = 0; j < 8; j++) acc[i][j] = (f32x4){0.f, 0.f, 0.f, 0.f};

#pragma unroll
  for (int c = 0; c < 8; c++) {
    const int k0 = c * 32;
    bf16x8 af[2];
    af[0] = *(const bf16x8*)&As[(wrow + mrem) * 264 + k0 + quad * 8];
    af[1] = *(const bf16x8*)&As[(wrow + 16 + mrem) * 264 + k0 + quad * 8];
#pragma unroll
    for (int j = 0; j < 8; j++) {
      bf16x8 bfr = *(const bf16x8*)(Wt + (size_t)(wcol + j * 16 + mrem) * CHN + k0 + quad * 8);
      acc[0][j] = __builtin_amdgcn_mfma_f32_16x16x32_bf16(af[0], bfr, acc[0][j], 0, 0, 0);
      acc[1][j] = __builtin_amdgcn_mfma_f32_16x16x32_bf16(af[1], bfr, acc[1][j], 0, 0, 0);
    }
  }

  const float omb = 1.f - beta;
#pragma unroll
  for (int i = 0; i < 2; i++) {
#pragma unroll
    for (int j = 0; j < 8; j++) {
      int lcol = wcol + j * 16 + mrem;
#pragma unroll
      for (int r = 0; r < 4; r++) {
        int lrow = wrow + i * 16 + quad * 4 + r;
        int grow = row0 + lrow;
        if (grow < N_NODES) {
          float xv = bf2f(As[lrow * 264 + lcol]);
          hout[(size_t)grow * CHN + lcol] = f2bf(fmaxf(omb * xv + beta * acc[i][j][r], 0.f));
        }
      }
    }
  }
}

// ---------------- out: out = h @ Wo + bo  (M=100000, K=256, N=40) ----------------
__global__ __launch_bounds__(256) void out_kernel(const short* __restrict__ h,
                                                  const float* __restrict__ W,
                                                  const float* __restrict__ b,
                                                  float* __restrict__ out) {
  __shared__ float xs[32][260];
  __shared__ float ws[64][40];
  const int row0 = blockIdx.x * 32;
  const int tid = threadIdx.x;
  for (int f = tid; f < 1024; f += 256) {
    int r = f >> 5;
    int c = (f & 31) * 8;
    bf16x8 v = *(const bf16x8*)(h + (size_t)(row0 + r) * CHN + c);
    float t0[8];
#pragma unroll
    for (int q = 0; q < 8; q++) t0[q] = bf2f(v[q]);
    *(float4*)&xs[r][c] = *(float4*)(t0);
    *(float4*)&xs[r][c + 4] = *(float4*)(t0 + 4);
  }
  const int r = tid >> 3;
  const int cg = (tid & 7) * 5;
  float acc[5];
#pragma unroll
  for (int j = 0; j < 5; j++) acc[j] = b[cg + j];
  for (int k0 = 0; k0 < CHN; k0 += 64) {
    for (int i = tid; i < 64 * 40; i += 256) {
      int k = i / 40, c = i % 40;
      ws[k][c] = W[(size_t)(k0 + k) * NCLASS + c];
    }
    __syncthreads();
#pragma unroll 8
    for (int k = 0; k < 64; k++) {
      float xv = xs[r][k0 + k];
#pragma unroll
      for (int j = 0; j < 5; j++) acc[j] += xv * ws[k][cg + j];
    }
    __syncthreads();
  }
  float* op = out + (size_t)(row0 + r) * NCLASS + cg;
#pragma unroll
  for (int j = 0; j < 5; j++) op[j] = acc[j];
}

extern "C" void kernel_launch(void* const* d_in, const int* in_sizes, int n_in,
                              void* d_out, int out_size, void* d_ws, size_t ws_size,
                              hipStream_t stream) {
  const float* x0 = (const float*)d_in[0];
  const float* x1 = (const float*)d_in[1];
  const int* ei = (const int*)d_in[2];
  const float* lw = (const float*)d_in[3];
  const float* lb = (const float*)d_in[4];
  const float* gw = (const float*)d_in[5];
  const float* ow = (const float*)d_in[6];
  const float* ob = (const float*)d_in[7];
  float* outp = (float*)d_out;

  const size_t NC = (size_t)N_NODES * CHN;
  short* h0 = (short*)d_ws;
  short* hb = h0 + NC;
  short* xb = hb + NC;
  short* linT = xb + NC;
  short* gcnT = linT + 2 * DHID * DIN;
  int* cnt = (int*)(gcnT + 8 * CHN * CHN);
  int* rowp = cnt + N_NODES;
  int* fill = rowp + N_NODES + 1;
  int* col = fill + N_NODES;
  int* bsums = col + N_EDGES;

  const int* src = ei;
  const int* dst = ei + N_EDGES;

  hipMemsetAsync(cnt, 0, N_NODES * sizeof(int), stream);
  hist_kernel<<<(N_EDGES + 255) / 256, 256, 0, stream>>>(dst, cnt);
  bscan1<<<SCAN_NB, 256, 0, stream>>>(cnt, rowp, bsums);
  bscan2<<<1, 64, 0, stream>>>(bsums, rowp);
  bscan3<<<SCAN_NB, 256, 0, stream>>>(rowp, fill, bsums);
  scatter_kernel<<<(N_EDGES + 255) / 256, 256, 0, stream>>>(src, dst, fill, col);
  prep_w_kernel<<<(2 * 128 * 256 + 8 * 256 * 256 + 255) / 256, 256, 0, stream>>>(lw, gw, linT, gcnT);

  dim3 lg((N_NODES + 63) / 64, 2);
  lin_mfma_kernel<<<lg, 256, 0, stream>>>(x0, x1, linT, lb, h0);

  const int nblk = (N_NODES + 63) / 64;
  const short* hin = h0;
  for (int l = 0; l < NLAYER; ++l) {
    float beta = logf(0.5f / (float)(l + 1) + 1.0f);
    agg_kernel<<<N_NODES / 4, 256, 0, stream>>>(hin, h0, rowp, col, xb);
    layer_gemm_v2<<<nblk, 256, 0, stream>>>(xb, gcnT + (size_t)l * CHN * CHN, hb, beta);
    hin = hb;
  }
  out_kernel<<<N_NODES / 32, 256, 0, stream>>>(hb, ow, ob, outp);
}